// Round 2
// baseline (107.297 us; speedup 1.0000x reference)
//
#include <hip/hip_runtime.h>

#define DEV __device__ __forceinline__

typedef unsigned short u16;
typedef __attribute__((ext_vector_type(8))) __bf16 bf16x8;
typedef __attribute__((ext_vector_type(4))) float f32x4;
typedef __attribute__((ext_vector_type(8))) unsigned short u16x8;
typedef __attribute__((ext_vector_type(4))) unsigned short u16x4;

// Problem constants: B=16, T=4096, Din=Dout=S=256
static constexpr int NB = 16;
static constexpr int NT = 4096;
static constexpr int NCH = 64;   // chunks per batch (L = 64)
static constexpr int LCH = 64;

DEV u16 f2bf(float f) {
  unsigned u = __builtin_bit_cast(unsigned, f);
  u += 0x7fffu + ((u >> 16) & 1u);
  return (u16)(u >> 16);
}
DEV float bf2f(u16 h) {
  unsigned u = ((unsigned)h) << 16;
  return __builtin_bit_cast(float, u);
}

DEV void gl_lds16(const void* gp, void* lp) {
  __builtin_amdgcn_global_load_lds(
      (__attribute__((address_space(1))) void*)(void*)gp,
      (__attribute__((address_space(3))) void*)lp, 16, 0, 0);
}

DEV u16x8 pack8(float4 a, float4 b) {
  u16x8 o;
  o[0] = f2bf(a.x); o[1] = f2bf(a.y); o[2] = f2bf(a.z); o[3] = f2bf(a.w);
  o[4] = f2bf(b.x); o[5] = f2bf(b.y); o[6] = f2bf(b.z); o[7] = f2bf(b.w);
  return o;
}

// ---------------- prep: a = tanh(a_raw); b,c,d -> bf16 ----------------
__global__ __launch_bounds__(256) void prep_k(const float* __restrict__ a_raw,
                                              const float* __restrict__ b,
                                              const float* __restrict__ c,
                                              const float* __restrict__ d,
                                              float* __restrict__ af,
                                              u16* __restrict__ bw,
                                              u16* __restrict__ cw,
                                              u16* __restrict__ dw) {
  int i = blockIdx.x * 256 + threadIdx.x;  // grid 256 -> i < 65536
  if (i < 256) af[i] = tanhf(a_raw[i]);
  bw[i] = f2bf(b[i]);
  cw[i] = f2bf(c[i]);
  dw[i] = f2bf(d[i]);
}

// ---------------- gemm1: Bu = u@b^T (swizzled bf16) and Ud = u@d^T (plain bf16) ----
// grid (512, 4): by 0/1 -> b-panel col halves (bu), by 2/3 -> d-panel halves (ud).
// 512 threads = 8 waves (2x4), wave tile 64x32, block tile 128x128, K=256 in 4 steps.
// A (u fp32) reg-staged -> bf16 -> swizzled LDS. B staged via global_load_lds with
// pre-swizzled source addresses.
__global__ __launch_bounds__(512) void gemm1_k(const float* __restrict__ u,
                                               const u16* __restrict__ bw,
                                               const u16* __restrict__ dw,
                                               u16* __restrict__ bu,
                                               u16* __restrict__ ud) {
  __shared__ u16 As[128 * 64];
  __shared__ u16 Bs[128 * 64];
  const int tid = threadIdx.x;
  const int lane = tid & 63;
  const int wid = tid >> 6;
  const int wr = wid >> 2, wc = wid & 3;
  const int bx = blockIdx.x;
  const int by = blockIdx.y;
  const bool dpanel = (by >= 2);
  const int col0 = (by & 1) * 128;
  const u16* W = dpanel ? dw : bw;
  const size_t row0 = (size_t)bx * 128;

  const int arow = tid >> 2;          // 0..127
  const int ak0 = (tid & 3) * 16;     // 0,16,32,48
  const float* uptr = u + (row0 + arow) * 256;
  const int s0 = (tid & 3) * 2;       // first of 2 A slots

  const f32x4 zero = {0.f, 0.f, 0.f, 0.f};
  f32x4 acc[4][2];
#pragma unroll
  for (int i = 0; i < 4; ++i) { acc[i][0] = zero; acc[i][1] = zero; }

#pragma unroll
  for (int kt = 0; kt < 4; ++kt) {
    const int kb = kt * 64;
    // A: 16 floats per thread
    float4 f0 = *reinterpret_cast<const float4*>(uptr + kb + ak0);
    float4 f1 = *reinterpret_cast<const float4*>(uptr + kb + ak0 + 4);
    float4 f2 = *reinterpret_cast<const float4*>(uptr + kb + ak0 + 8);
    float4 f3 = *reinterpret_cast<const float4*>(uptr + kb + ak0 + 12);
    // B: 16KB via gl_lds, 2 rounds, pre-swizzled source
#pragma unroll
    for (int r = 0; r < 2; ++r) {
      int brow = r * 64 + (tid >> 3);
      int sc = (tid & 7) ^ (brow & 7);
      gl_lds16(W + (size_t)(col0 + brow) * 256 + kb + sc * 8,
               (char*)Bs + r * 8192 + wid * 1024);
    }
    // A: convert + swizzled LDS write
    *reinterpret_cast<u16x8*>(&As[arow * 64 + ((s0) ^ (arow & 7)) * 8]) = pack8(f0, f1);
    *reinterpret_cast<u16x8*>(&As[arow * 64 + ((s0 + 1) ^ (arow & 7)) * 8]) = pack8(f2, f3);
    __syncthreads();
#pragma unroll
    for (int kk = 0; kk < 2; ++kk) {
      const int ks = kk * 4 + (lane >> 4);
      bf16x8 afr[4], bfr[2];
#pragma unroll
      for (int mi = 0; mi < 4; ++mi) {
        int ar = wr * 64 + mi * 16 + (lane & 15);
        afr[mi] = *reinterpret_cast<const bf16x8*>(&As[ar * 64 + (ks ^ (ar & 7)) * 8]);
      }
#pragma unroll
      for (int ni = 0; ni < 2; ++ni) {
        int nr = wc * 32 + ni * 16 + (lane & 15);
        bfr[ni] = *reinterpret_cast<const bf16x8*>(&Bs[nr * 64 + (ks ^ (nr & 7)) * 8]);
      }
#pragma unroll
      for (int mi = 0; mi < 4; ++mi)
#pragma unroll
        for (int ni = 0; ni < 2; ++ni)
          acc[mi][ni] = __builtin_amdgcn_mfma_f32_16x16x32_bf16(
              afr[mi], bfr[ni], acc[mi][ni], 0, 0, 0);
    }
    if (kt < 3) __syncthreads();
  }

  // Epilogue: C/D layout col = lane&15, row = (lane>>4)*4 + q
#pragma unroll
  for (int mi = 0; mi < 4; ++mi) {
    int rlb = wr * 64 + mi * 16 + (lane >> 4) * 4;
#pragma unroll
    for (int ni = 0; ni < 2; ++ni) {
      int col = col0 + wc * 32 + ni * 16 + (lane & 15);
#pragma unroll
      for (int q = 0; q < 4; ++q) {
        size_t R = row0 + rlb + q;
        u16 h = f2bf(acc[mi][ni][q]);
        if (!dpanel)
          bu[R * 256 + (((col >> 3) ^ ((int)(R) & 7)) * 8) + (col & 7)] = h;
        else
          ud[R * 256 + col] = h;
      }
    }
  }
}

// ---------------- scan1: per-chunk carries from swizzled bu ----------------
// block = 256 thr = 4 chunks x 64 thr; each thread handles 4 states (u16x4 loads)
__global__ __launch_bounds__(256) void scan1_k(const u16* __restrict__ bu,
                                               const float* __restrict__ af,
                                               float* __restrict__ carry) {
  const int tid = threadIdx.x;
  const int g = blockIdx.x * 4 + (tid >> 6);  // global chunk, row base = g*64
  const int s4 = (tid & 63) * 4;
  const size_t rb = (size_t)g * 64;
  float a0 = af[s4], a1 = af[s4 + 1], a2 = af[s4 + 2], a3 = af[s4 + 3];
  float x0 = 0.f, x1 = 0.f, x2 = 0.f, x3 = 0.f;
  for (int t = 0; t < LCH; ++t) {
    size_t idx = (rb + t) * 256 + ((s4 >> 3) ^ (t & 7)) * 8 + (s4 & 7);
    u16x4 v = *reinterpret_cast<const u16x4*>(bu + idx);
    x0 = fmaf(a0, x0, bf2f(v[0]));
    x1 = fmaf(a1, x1, bf2f(v[1]));
    x2 = fmaf(a2, x2, bf2f(v[2]));
    x3 = fmaf(a3, x3, bf2f(v[3]));
  }
  float4 o = {x0, x1, x2, x3};
  *reinterpret_cast<float4*>(carry + (size_t)g * 256 + s4) = o;
}

// ---------------- scan2: exclusive scan of carries over 64 chunks ----------------
__global__ __launch_bounds__(256) void scan2_k(const float* __restrict__ carry,
                                               const float* __restrict__ af,
                                               float* __restrict__ initb) {
  int b = blockIdx.x;  // 16
  int s = threadIdx.x;
  float a = af[s];
  float aL = a;
#pragma unroll
  for (int i = 0; i < 6; ++i) aL *= aL;  // a^64
  float x = 0.f;
  for (int k = 0; k < NCH; ++k) {
    size_t idx = ((size_t)(b * NCH + k)) * 256 + s;
    float cv = carry[idx];
    initb[idx] = x;
    x = fmaf(aL, x, cv);
  }
}

// ---------------- gemm2: y = xs@c^T + Ud, with in-LDS xs reconstruction --------
// grid (512, 2): bx = row tile (= chunk pair), by = col half. 512 thr, 8 waves 2x4,
// wave tile 64x32. LDS: XS [128][256] bf16 swizzled (64KB) + CS [128][64] (16KB).
__global__ __launch_bounds__(512) void gemm2_k(const u16* __restrict__ bu,
                                               const u16* __restrict__ cw,
                                               const u16* __restrict__ ud,
                                               const float* __restrict__ af,
                                               const float* __restrict__ initb,
                                               float* __restrict__ y) {
  __shared__ u16 XS[128 * 256];
  __shared__ u16 CS[128 * 64];
  const int tid = threadIdx.x;
  const int lane = tid & 63;
  const int wid = tid >> 6;
  const int wr = wid >> 2, wc = wid & 3;
  const int bx = blockIdx.x;          // rows bx*128..+128 ; chunks 2bx, 2bx+1
  const int col0 = blockIdx.y * 128;

  // stage bu tile (linear copy; data pre-swizzled in global)
  const char* src = (const char*)bu + (size_t)bx * 65536;
#pragma unroll
  for (int j = 0; j < 8; ++j)
    gl_lds16(src + j * 8192 + tid * 16, (char*)XS + j * 8192 + wid * 1024);
  // stage C step 0
#pragma unroll
  for (int r = 0; r < 2; ++r) {
    int brow = r * 64 + (tid >> 3);
    int sc = (tid & 7) ^ (brow & 7);
    gl_lds16(cw + (size_t)(col0 + brow) * 256 + 0 + sc * 8,
             (char*)CS + r * 8192 + wid * 1024);
  }
  __syncthreads();

  // ---- recon xs in place: 2 chunk halves x 256 states ----
  {
    const int hf = tid >> 8;        // 0/1
    const int s = tid & 255;
    const float a = af[s];
    float x = initb[(size_t)(bx * 2 + hf) * 256 + s];
    const int r0 = hf * 64;
    const int slot = s >> 3;
    const int off = (s & 7);
#pragma unroll 8
    for (int t = 0; t < 64; ++t) {
      int r = r0 + t;
      int bi = r * 256 + ((slot ^ (r & 7)) * 8) + off;
      x = fmaf(a, x, bf2f(XS[bi]));
      XS[bi] = f2bf(x);
    }
  }

  // ---- init acc from ud (global, overlaps recon of other waves) ----
  f32x4 acc[4][2];
#pragma unroll
  for (int mi = 0; mi < 4; ++mi) {
    int rlb = wr * 64 + mi * 16 + (lane >> 4) * 4;
#pragma unroll
    for (int ni = 0; ni < 2; ++ni) {
      int col = col0 + wc * 32 + ni * 16 + (lane & 15);
#pragma unroll
      for (int q = 0; q < 4; ++q)
        acc[mi][ni][q] = bf2f(ud[(size_t)(bx * 128 + rlb + q) * 256 + col]);
    }
  }
  __syncthreads();

  // ---- K loop over c (K=256, 4 steps) ----
#pragma unroll
  for (int kt = 0; kt < 4; ++kt) {
#pragma unroll
    for (int kk = 0; kk < 2; ++kk) {
      const int ksl = kk * 4 + (lane >> 4);       // local slot in CS
      const int ksg = kt * 8 + ksl;               // global slot in XS
      bf16x8 afr[4], bfr[2];
#pragma unroll
      for (int mi = 0; mi < 4; ++mi) {
        int ar = wr * 64 + mi * 16 + (lane & 15);
        afr[mi] = *reinterpret_cast<const bf16x8*>(&XS[ar * 256 + ((ksg ^ (ar & 7)) * 8)]);
      }
#pragma unroll
      for (int ni = 0; ni < 2; ++ni) {
        int nr = wc * 32 + ni * 16 + (lane & 15);
        bfr[ni] = *reinterpret_cast<const bf16x8*>(&CS[nr * 64 + ((ksl ^ (nr & 7)) * 8)]);
      }
#pragma unroll
      for (int mi = 0; mi < 4; ++mi)
#pragma unroll
        for (int ni = 0; ni < 2; ++ni)
          acc[mi][ni] = __builtin_amdgcn_mfma_f32_16x16x32_bf16(
              afr[mi], bfr[ni], acc[mi][ni], 0, 0, 0);
    }
    if (kt < 3) {
      __syncthreads();  // readers done with CS
#pragma unroll
      for (int r = 0; r < 2; ++r) {
        int brow = r * 64 + (tid >> 3);
        int sc = (tid & 7) ^ (brow & 7);
        gl_lds16(cw + (size_t)(col0 + brow) * 256 + (kt + 1) * 64 + sc * 8,
                 (char*)CS + r * 8192 + wid * 1024);
      }
      __syncthreads();  // staged (vmcnt drained)
    }
  }

  // ---- epilogue: y fp32 ----
#pragma unroll
  for (int mi = 0; mi < 4; ++mi) {
    int rlb = wr * 64 + mi * 16 + (lane >> 4) * 4;
#pragma unroll
    for (int ni = 0; ni < 2; ++ni) {
      int col = col0 + wc * 32 + ni * 16 + (lane & 15);
#pragma unroll
      for (int q = 0; q < 4; ++q)
        y[(size_t)(bx * 128 + rlb + q) * 256 + col] = acc[mi][ni][q];
    }
  }
}

extern "C" void kernel_launch(void* const* d_in, const int* in_sizes, int n_in,
                              void* d_out, int out_size, void* d_ws, size_t ws_size,
                              hipStream_t stream) {
  const float* u = (const float*)d_in[0];
  const float* a_raw = (const float*)d_in[1];
  const float* b = (const float*)d_in[2];
  const float* c = (const float*)d_in[3];
  const float* d = (const float*)d_in[4];
  float* y = (float*)d_out;
  char* ws = (char*)d_ws;

  const size_t MB = 1u << 20;
  float* af = (float*)(ws);                       // 1 KB
  u16* bw = (u16*)(ws + 4096);                    // 128 KB
  u16* cw = (u16*)(ws + 4096 + 131072);           // 128 KB
  u16* dw = (u16*)(ws + 4096 + 2 * 131072);       // 128 KB
  u16* bu = (u16*)(ws + 1 * MB);                  // 32 MB (swizzled)
  u16* ud = (u16*)(ws + 33 * MB);                 // 32 MB
  float* carry = (float*)(ws + 65 * MB);          // 1 MB
  float* initb = (float*)(ws + 66 * MB);          // 1 MB

  prep_k<<<256, 256, 0, stream>>>(a_raw, b, c, d, af, bw, cw, dw);
  gemm1_k<<<dim3(512, 4), 512, 0, stream>>>(u, bw, dw, bu, ud);
  scan1_k<<<256, 256, 0, stream>>>(bu, af, carry);
  scan2_k<<<16, 256, 0, stream>>>(carry, af, initb);
  gemm2_k<<<dim3(512, 2), 512, 0, stream>>>(bu, cw, ud, af, initb, y);
}

// Round 3
// 91.534 us; speedup vs baseline: 1.1722x; 1.1722x over previous
//
#include <hip/hip_runtime.h>

#define DEV __device__ __forceinline__

typedef unsigned short u16;
typedef __attribute__((ext_vector_type(8))) __bf16 bf16x8;
typedef __attribute__((ext_vector_type(4))) float f32x4;
typedef __attribute__((ext_vector_type(8))) unsigned short u16x8;
typedef __attribute__((ext_vector_type(4))) unsigned short u16x4;

// Problem constants: B=16, T=4096, Din=Dout=S=256
static constexpr int NB = 16;
static constexpr int NT = 4096;
static constexpr int NCH = 64;   // chunks per batch (L = 64)
static constexpr int LCH = 64;

DEV u16 f2bf(float f) {
  unsigned u = __builtin_bit_cast(unsigned, f);
  u += 0x7fffu + ((u >> 16) & 1u);
  return (u16)(u >> 16);
}
DEV float bf2f(u16 h) {
  unsigned u = ((unsigned)h) << 16;
  return __builtin_bit_cast(float, u);
}

DEV void gl_lds16(const void* gp, void* lp) {
  __builtin_amdgcn_global_load_lds(
      (__attribute__((address_space(1))) void*)(void*)gp,
      (__attribute__((address_space(3))) void*)lp, 16, 0, 0);
}

// ---------------- prep: a = tanh(a_raw); wq = [b;d] bf16; c -> bf16 ----------------
__global__ __launch_bounds__(256) void prep_k(const float* __restrict__ a_raw,
                                              const float* __restrict__ b,
                                              const float* __restrict__ c,
                                              const float* __restrict__ d,
                                              float* __restrict__ af,
                                              u16* __restrict__ wq,
                                              u16* __restrict__ cw) {
  int i = blockIdx.x * 256 + threadIdx.x;  // grid 256 -> i < 65536
  if (i < 256) af[i] = tanhf(a_raw[i]);
  wq[i] = f2bf(b[i]);
  wq[65536 + i] = f2bf(d[i]);
  cw[i] = f2bf(c[i]);
}

// ---------------- gemm1: [Bu | Ud] = u @ [b;d]^T, + per-chunk scan carries --------
// 1024 blocks (bx = one 64-row chunk), 1024 threads = 16 waves, wave tile 64x32.
// u (fp32) read ONCE, reg-staged -> bf16 -> swizzled LDS. Weights via gl_lds with
// pre-swizzled source addresses. Waves 0-7 -> bu cols (written pre-swizzled for
// gemm2's linear gl_lds), waves 8-15 -> ud cols (plain). Waves 0-7 also compute
// carry[chunk][s] = sum_t a_s^(63-t) * Bu[t][s] in-register (squaring chain +
// shfl_xor reduce over the 4 lane-groups that hold the 64 timesteps).
__global__ __launch_bounds__(1024) void gemm1_k(const float* __restrict__ u,
                                                const u16* __restrict__ wq,
                                                const float* __restrict__ af,
                                                u16* __restrict__ bu,
                                                u16* __restrict__ ud,
                                                float* __restrict__ carry) {
  __shared__ u16 As[64 * 64];    // 8 KB, swizzled
  __shared__ u16 Ws[512 * 64];   // 64 KB, swizzled
  const int tid = threadIdx.x;
  const int lane = tid & 63;
  const int wid = tid >> 6;      // 0..15 = wave col group (32 cols each)
  const int bx = blockIdx.x;     // chunk index
  const size_t row0 = (size_t)bx * 64;

  // A staging map: 4 floats/thread
  const int arow = tid >> 4;           // 0..63
  const int ak = (tid & 15) * 4;       // k offset
  const int abyte = arow * 128 + ((((tid & 15) >> 1) ^ (arow & 7)) * 16) + (tid & 1) * 8;

  const f32x4 zero = {0.f, 0.f, 0.f, 0.f};
  f32x4 acc[4][2];
#pragma unroll
  for (int i = 0; i < 4; ++i) { acc[i][0] = zero; acc[i][1] = zero; }

#pragma unroll
  for (int kt = 0; kt < 4; ++kt) {
    const int kb = kt * 64;
    float4 av = *reinterpret_cast<const float4*>(u + (row0 + arow) * 256 + kb + ak);
#pragma unroll
    for (int r = 0; r < 4; ++r) {
      int wrow = r * 128 + (tid >> 3);
      int sc = (tid & 7) ^ (wrow & 7);
      gl_lds16(wq + (size_t)wrow * 256 + kb + sc * 8,
               (char*)Ws + r * 16384 + wid * 1024);
    }
    u16x4 a4;
    a4[0] = f2bf(av.x); a4[1] = f2bf(av.y); a4[2] = f2bf(av.z); a4[3] = f2bf(av.w);
    *reinterpret_cast<u16x4*>((char*)As + abyte) = a4;
    __syncthreads();
#pragma unroll
    for (int kk = 0; kk < 2; ++kk) {
      const int ks = kk * 4 + (lane >> 4);
      bf16x8 afr[4], bfr[2];
#pragma unroll
      for (int mi = 0; mi < 4; ++mi) {
        int ar = mi * 16 + (lane & 15);
        afr[mi] = *reinterpret_cast<const bf16x8*>(
            (const char*)As + ar * 128 + ((ks ^ (ar & 7)) * 16));
      }
#pragma unroll
      for (int ni = 0; ni < 2; ++ni) {
        int br = wid * 32 + ni * 16 + (lane & 15);
        bfr[ni] = *reinterpret_cast<const bf16x8*>(
            (const char*)Ws + br * 128 + ((ks ^ (br & 7)) * 16));
      }
#pragma unroll
      for (int mi = 0; mi < 4; ++mi)
#pragma unroll
        for (int ni = 0; ni < 2; ++ni)
          acc[mi][ni] = __builtin_amdgcn_mfma_f32_16x16x32_bf16(
              afr[mi], bfr[ni], acc[mi][ni], 0, 0, 0);
    }
    if (kt < 3) __syncthreads();
  }

  // ---- write outputs. C/D layout: col = lane&15, row = (lane>>4)*4 + q ----
#pragma unroll
  for (int mi = 0; mi < 4; ++mi) {
    int rl = mi * 16 + (lane >> 4) * 4;
#pragma unroll
    for (int ni = 0; ni < 2; ++ni) {
      int col = wid * 32 + ni * 16 + (lane & 15);
#pragma unroll
      for (int q = 0; q < 4; ++q) {
        size_t R = row0 + rl + q;
        u16 h = f2bf(acc[mi][ni][q]);
        if (wid < 8)
          bu[R * 256 + (((col >> 3) ^ ((int)R & 7)) * 8) + (col & 7)] = h;
        else
          ud[R * 256 + (col - 256)] = h;
      }
    }
  }

  // ---- chunk carry: carry[bx][s] = sum_t a_s^(63-t) Bu[t][s] ----
  if (wid < 8) {
    const int tb = (lane >> 4) * 4;  // this lane-group's timestep base within frag
#pragma unroll
    for (int ni = 0; ni < 2; ++ni) {
      int col = wid * 32 + ni * 16 + (lane & 15);
      float a = af[col];
      float c2 = a * a, c4 = c2 * c2, c8 = c4 * c4;
      float a12 = c8 * c4;
      float a13 = a12 * a;
      // base = a^(12 - tb): exponent of weight for (mi=3, q=3) where t = 51+tb
      float base = (tb == 0) ? a12 : (tb == 4) ? c8 : (tb == 8) ? c4 : 1.0f;
      float p = base, s = 0.f;
#pragma unroll
      for (int mi = 3; mi >= 0; --mi) {
#pragma unroll
        for (int q = 3; q >= 0; --q) {
          s = fmaf(p, acc[mi][ni][q], s);
          if (q) p *= a;
        }
        if (mi) p *= a13;  // exponent +13: from (mi,q=0) to (mi-1,q=3)
      }
      s += __shfl_xor(s, 16, 64);
      s += __shfl_xor(s, 32, 64);
      if ((lane >> 4) == 0) carry[(size_t)bx * 256 + col] = s;
    }
  }
}

// ---------------- scan2: exclusive scan of carries over 64 chunks ----------------
__global__ __launch_bounds__(256) void scan2_k(const float* __restrict__ carry,
                                               const float* __restrict__ af,
                                               float* __restrict__ initb) {
  int b = blockIdx.x;  // 16
  int s = threadIdx.x;
  float a = af[s];
  float aL = a;
#pragma unroll
  for (int i = 0; i < 6; ++i) aL *= aL;  // a^64
  float x = 0.f;
  for (int k = 0; k < NCH; ++k) {
    size_t idx = ((size_t)(b * NCH + k)) * 256 + s;
    float cv = carry[idx];
    initb[idx] = x;
    x = fmaf(aL, x, cv);
  }
}

// ---------------- gemm2: y = xs@c^T + Ud, with in-LDS xs reconstruction --------
// grid (512, 2): bx = row tile (= chunk pair), by = col half. 512 thr, 8 waves 2x4,
// wave tile 64x32. LDS: XS [128][256] bf16 swizzled (64KB) + CS [128][64] (16KB).
__global__ __launch_bounds__(512) void gemm2_k(const u16* __restrict__ bu,
                                               const u16* __restrict__ cw,
                                               const u16* __restrict__ ud,
                                               const float* __restrict__ af,
                                               const float* __restrict__ initb,
                                               float* __restrict__ y) {
  __shared__ u16 XS[128 * 256];
  __shared__ u16 CS[128 * 64];
  const int tid = threadIdx.x;
  const int lane = tid & 63;
  const int wid = tid >> 6;
  const int wr = wid >> 2, wc = wid & 3;
  const int bx = blockIdx.x;          // rows bx*128..+128 ; chunks 2bx, 2bx+1
  const int col0 = blockIdx.y * 128;

  // stage bu tile (linear copy; data pre-swizzled in global)
  const char* src = (const char*)bu + (size_t)bx * 65536;
#pragma unroll
  for (int j = 0; j < 8; ++j)
    gl_lds16(src + j * 8192 + tid * 16, (char*)XS + j * 8192 + wid * 1024);
  // stage C step 0
#pragma unroll
  for (int r = 0; r < 2; ++r) {
    int brow = r * 64 + (tid >> 3);
    int sc = (tid & 7) ^ (brow & 7);
    gl_lds16(cw + (size_t)(col0 + brow) * 256 + 0 + sc * 8,
             (char*)CS + r * 8192 + wid * 1024);
  }
  __syncthreads();

  // ---- recon xs in place: 2 chunk halves x 256 states ----
  {
    const int hf = tid >> 8;        // 0/1
    const int s = tid & 255;
    const float a = af[s];
    float x = initb[(size_t)(bx * 2 + hf) * 256 + s];
    const int r0 = hf * 64;
    const int slot = s >> 3;
    const int off = (s & 7);
#pragma unroll 8
    for (int t = 0; t < 64; ++t) {
      int r = r0 + t;
      int bi = r * 256 + ((slot ^ (r & 7)) * 8) + off;
      x = fmaf(a, x, bf2f(XS[bi]));
      XS[bi] = f2bf(x);
    }
  }

  // ---- init acc from ud (global, overlaps recon of other waves) ----
  f32x4 acc[4][2];
#pragma unroll
  for (int mi = 0; mi < 4; ++mi) {
    int rlb = wr * 64 + mi * 16 + (lane >> 4) * 4;
#pragma unroll
    for (int ni = 0; ni < 2; ++ni) {
      int col = col0 + wc * 32 + ni * 16 + (lane & 15);
#pragma unroll
      for (int q = 0; q < 4; ++q)
        acc[mi][ni][q] = bf2f(ud[(size_t)(bx * 128 + rlb + q) * 256 + col]);
    }
  }
  __syncthreads();

  // ---- K loop over c (K=256, 4 steps) ----
#pragma unroll
  for (int kt = 0; kt < 4; ++kt) {
#pragma unroll
    for (int kk = 0; kk < 2; ++kk) {
      const int ksl = kk * 4 + (lane >> 4);       // local slot in CS
      const int ksg = kt * 8 + ksl;               // global slot in XS
      bf16x8 afr[4], bfr[2];
#pragma unroll
      for (int mi = 0; mi < 4; ++mi) {
        int ar = wr * 64 + mi * 16 + (lane & 15);
        afr[mi] = *reinterpret_cast<const bf16x8*>(&XS[ar * 256 + ((ksg ^ (ar & 7)) * 8)]);
      }
#pragma unroll
      for (int ni = 0; ni < 2; ++ni) {
        int nr = wc * 32 + ni * 16 + (lane & 15);
        bfr[ni] = *reinterpret_cast<const bf16x8*>(&CS[nr * 64 + ((ksl ^ (nr & 7)) * 8)]);
      }
#pragma unroll
      for (int mi = 0; mi < 4; ++mi)
#pragma unroll
        for (int ni = 0; ni < 2; ++ni)
          acc[mi][ni] = __builtin_amdgcn_mfma_f32_16x16x32_bf16(
              afr[mi], bfr[ni], acc[mi][ni], 0, 0, 0);
    }
    if (kt < 3) {
      __syncthreads();  // readers done with CS
#pragma unroll
      for (int r = 0; r < 2; ++r) {
        int brow = r * 64 + (tid >> 3);
        int sc = (tid & 7) ^ (brow & 7);
        gl_lds16(cw + (size_t)(col0 + brow) * 256 + (kt + 1) * 64 + sc * 8,
                 (char*)CS + r * 8192 + wid * 1024);
      }
      __syncthreads();  // staged (vmcnt drained)
    }
  }

  // ---- epilogue: y fp32 ----
#pragma unroll
  for (int mi = 0; mi < 4; ++mi) {
    int rlb = wr * 64 + mi * 16 + (lane >> 4) * 4;
#pragma unroll
    for (int ni = 0; ni < 2; ++ni) {
      int col = col0 + wc * 32 + ni * 16 + (lane & 15);
#pragma unroll
      for (int q = 0; q < 4; ++q)
        y[(size_t)(bx * 128 + rlb + q) * 256 + col] = acc[mi][ni][q];
    }
  }
}

extern "C" void kernel_launch(void* const* d_in, const int* in_sizes, int n_in,
                              void* d_out, int out_size, void* d_ws, size_t ws_size,
                              hipStream_t stream) {
  const float* u = (const float*)d_in[0];
  const float* a_raw = (const float*)d_in[1];
  const float* b = (const float*)d_in[2];
  const float* c = (const float*)d_in[3];
  const float* d = (const float*)d_in[4];
  float* y = (float*)d_out;
  char* ws = (char*)d_ws;

  const size_t MB = 1u << 20;
  float* af = (float*)(ws);                       // 1 KB
  u16* wq = (u16*)(ws + 65536);                   // 256 KB  [b;d] stacked
  u16* cw = (u16*)(ws + 65536 + 262144);          // 128 KB
  u16* bu = (u16*)(ws + 1 * MB);                  // 32 MB (swizzled)
  u16* ud = (u16*)(ws + 33 * MB);                 // 32 MB
  float* carry = (float*)(ws + 65 * MB);          // 1 MB
  float* initb = (float*)(ws + 66 * MB);          // 1 MB

  prep_k<<<256, 256, 0, stream>>>(a_raw, b, c, d, af, wq, cw);
  gemm1_k<<<1024, 1024, 0, stream>>>(u, wq, af, bu, ud, carry);
  scan2_k<<<16, 256, 0, stream>>>(carry, af, initb);
  gemm2_k<<<dim3(512, 2), 512, 0, stream>>>(bu, cw, ud, af, initb, y);
}

// Round 4
// 90.713 us; speedup vs baseline: 1.1828x; 1.0091x over previous
//
#include <hip/hip_runtime.h>

#define DEV __device__ __forceinline__

typedef unsigned short u16;
typedef __attribute__((ext_vector_type(8))) __bf16 bf16x8;
typedef __attribute__((ext_vector_type(4))) float f32x4;
typedef __attribute__((ext_vector_type(8))) unsigned short u16x8;
typedef __attribute__((ext_vector_type(4))) unsigned short u16x4;

// Problem constants: B=16, T=4096, Din=Dout=S=256
static constexpr int NB = 16;
static constexpr int NT = 4096;
static constexpr int NCH = 64;   // chunks per batch (L = 64)
static constexpr int LCH = 64;

DEV u16 f2bf(float f) {
  unsigned u = __builtin_bit_cast(unsigned, f);
  u += 0x7fffu + ((u >> 16) & 1u);
  return (u16)(u >> 16);
}
DEV float bf2f(u16 h) {
  unsigned u = ((unsigned)h) << 16;
  return __builtin_bit_cast(float, u);
}

DEV void gl_lds16(const void* gp, void* lp) {
  __builtin_amdgcn_global_load_lds(
      (__attribute__((address_space(1))) void*)(void*)gp,
      (__attribute__((address_space(3))) void*)lp, 16, 0, 0);
}

// ---------------- prep: a = tanh(a_raw); wq = [b;d] bf16; c -> bf16 ----------------
__global__ __launch_bounds__(256) void prep_k(const float* __restrict__ a_raw,
                                              const float* __restrict__ b,
                                              const float* __restrict__ c,
                                              const float* __restrict__ d,
                                              float* __restrict__ af,
                                              u16* __restrict__ wq,
                                              u16* __restrict__ cw) {
  int i = blockIdx.x * 256 + threadIdx.x;  // grid 256 -> i < 65536
  if (i < 256) af[i] = tanhf(a_raw[i]);
  wq[i] = f2bf(b[i]);
  wq[65536 + i] = f2bf(d[i]);
  cw[i] = f2bf(c[i]);
}

// ---------------- gemm1: [Bu | Ud] = u @ [b;d]^T, + per-chunk scan carries --------
// 1024 blocks (bx = one 64-row chunk), 1024 threads = 16 waves, wave tile 64x32.
// __launch_bounds__(1024, 4): 16 waves/CU target -> 128 VGPR cap, NO acc spill
// (VGPR=40 + scratch-spilled accumulators was the R2/R3 64us wall).
__global__ __launch_bounds__(1024, 4) void gemm1_k(const float* __restrict__ u,
                                                   const u16* __restrict__ wq,
                                                   const float* __restrict__ af,
                                                   u16* __restrict__ bu,
                                                   u16* __restrict__ ud,
                                                   float* __restrict__ carry) {
  __shared__ u16 As[64 * 64];    // 8 KB, swizzled
  __shared__ u16 Ws[512 * 64];   // 64 KB, swizzled
  const int tid = threadIdx.x;
  const int lane = tid & 63;
  const int wid = tid >> 6;      // 0..15 = wave col group (32 cols each)
  const int bx = blockIdx.x;     // chunk index
  const size_t row0 = (size_t)bx * 64;

  // A staging map: 4 floats/thread
  const int arow = tid >> 4;           // 0..63
  const int ak = (tid & 15) * 4;       // k offset
  const int abyte = arow * 128 + ((((tid & 15) >> 1) ^ (arow & 7)) * 16) + (tid & 1) * 8;

  const f32x4 zero = {0.f, 0.f, 0.f, 0.f};
  f32x4 acc[4][2];
#pragma unroll
  for (int i = 0; i < 4; ++i) { acc[i][0] = zero; acc[i][1] = zero; }

#pragma unroll
  for (int kt = 0; kt < 4; ++kt) {
    const int kb = kt * 64;
    float4 av = *reinterpret_cast<const float4*>(u + (row0 + arow) * 256 + kb + ak);
#pragma unroll
    for (int r = 0; r < 4; ++r) {
      int wrow = r * 128 + (tid >> 3);
      int sc = (tid & 7) ^ (wrow & 7);
      gl_lds16(wq + (size_t)wrow * 256 + kb + sc * 8,
               (char*)Ws + r * 16384 + wid * 1024);
    }
    u16x4 a4;
    a4[0] = f2bf(av.x); a4[1] = f2bf(av.y); a4[2] = f2bf(av.z); a4[3] = f2bf(av.w);
    *reinterpret_cast<u16x4*>((char*)As + abyte) = a4;
    __syncthreads();
#pragma unroll
    for (int kk = 0; kk < 2; ++kk) {
      const int ks = kk * 4 + (lane >> 4);
      bf16x8 afr[4], bfr[2];
#pragma unroll
      for (int mi = 0; mi < 4; ++mi) {
        int ar = mi * 16 + (lane & 15);
        afr[mi] = *reinterpret_cast<const bf16x8*>(
            (const char*)As + ar * 128 + ((ks ^ (ar & 7)) * 16));
      }
#pragma unroll
      for (int ni = 0; ni < 2; ++ni) {
        int br = wid * 32 + ni * 16 + (lane & 15);
        bfr[ni] = *reinterpret_cast<const bf16x8*>(
            (const char*)Ws + br * 128 + ((ks ^ (br & 7)) * 16));
      }
#pragma unroll
      for (int mi = 0; mi < 4; ++mi)
#pragma unroll
        for (int ni = 0; ni < 2; ++ni)
          acc[mi][ni] = __builtin_amdgcn_mfma_f32_16x16x32_bf16(
              afr[mi], bfr[ni], acc[mi][ni], 0, 0, 0);
    }
    if (kt < 3) __syncthreads();
  }

  // ---- write outputs. C/D layout: col = lane&15, row = (lane>>4)*4 + q ----
#pragma unroll
  for (int mi = 0; mi < 4; ++mi) {
    int rl = mi * 16 + (lane >> 4) * 4;
#pragma unroll
    for (int ni = 0; ni < 2; ++ni) {
      int col = wid * 32 + ni * 16 + (lane & 15);
#pragma unroll
      for (int q = 0; q < 4; ++q) {
        size_t R = row0 + rl + q;
        u16 h = f2bf(acc[mi][ni][q]);
        if (wid < 8)
          bu[R * 256 + (((col >> 3) ^ ((int)R & 7)) * 8) + (col & 7)] = h;
        else
          ud[R * 256 + (col - 256)] = h;
      }
    }
  }

  // ---- chunk carry: carry[bx][s] = sum_t a_s^(63-t) Bu[t][s] ----
  if (wid < 8) {
    const int tb = (lane >> 4) * 4;  // this lane-group's timestep base within frag
#pragma unroll
    for (int ni = 0; ni < 2; ++ni) {
      int col = wid * 32 + ni * 16 + (lane & 15);
      float a = af[col];
      float c2 = a * a, c4 = c2 * c2, c8 = c4 * c4;
      float a12 = c8 * c4;
      float a13 = a12 * a;
      // base = a^(12 - tb): exponent of weight for (mi=3, q=3) where t = 51+tb
      float base = (tb == 0) ? a12 : (tb == 4) ? c8 : (tb == 8) ? c4 : 1.0f;
      float p = base, s = 0.f;
#pragma unroll
      for (int mi = 3; mi >= 0; --mi) {
#pragma unroll
        for (int q = 3; q >= 0; --q) {
          s = fmaf(p, acc[mi][ni][q], s);
          if (q) p *= a;
        }
        if (mi) p *= a13;  // exponent +13: from (mi,q=0) to (mi-1,q=3)
      }
      s += __shfl_xor(s, 16, 64);
      s += __shfl_xor(s, 32, 64);
      if ((lane >> 4) == 0) carry[(size_t)bx * 256 + col] = s;
    }
  }
}

// ---------------- scan2: exclusive scan of carries over 64 chunks ----------------
__global__ __launch_bounds__(256) void scan2_k(const float* __restrict__ carry,
                                               const float* __restrict__ af,
                                               float* __restrict__ initb) {
  int b = blockIdx.x;  // 16
  int s = threadIdx.x;
  float a = af[s];
  float aL = a;
#pragma unroll
  for (int i = 0; i < 6; ++i) aL *= aL;  // a^64
  float x = 0.f;
  for (int k = 0; k < NCH; ++k) {
    size_t idx = ((size_t)(b * NCH + k)) * 256 + s;
    float cv = carry[idx];
    initb[idx] = x;
    x = fmaf(aL, x, cv);
  }
}

// ---------------- gemm2: y = xs@c^T + Ud, with in-LDS xs reconstruction --------
// grid (512, 2): bx = row tile (= chunk pair), by = col half. 512 thr, 8 waves 2x4,
// wave tile 64x32. LDS: XS [128][256] bf16 swizzled (64KB) + CS [128][64] (16KB).
// __launch_bounds__(512, 4): 128 VGPR cap, no acc spill.
__global__ __launch_bounds__(512, 4) void gemm2_k(const u16* __restrict__ bu,
                                                  const u16* __restrict__ cw,
                                                  const u16* __restrict__ ud,
                                                  const float* __restrict__ af,
                                                  const float* __restrict__ initb,
                                                  float* __restrict__ y) {
  __shared__ u16 XS[128 * 256];
  __shared__ u16 CS[128 * 64];
  const int tid = threadIdx.x;
  const int lane = tid & 63;
  const int wid = tid >> 6;
  const int wr = wid >> 2, wc = wid & 3;
  const int bx = blockIdx.x;          // rows bx*128..+128 ; chunks 2bx, 2bx+1
  const int col0 = blockIdx.y * 128;

  // stage bu tile (linear copy; data pre-swizzled in global)
  const char* src = (const char*)bu + (size_t)bx * 65536;
#pragma unroll
  for (int j = 0; j < 8; ++j)
    gl_lds16(src + j * 8192 + tid * 16, (char*)XS + j * 8192 + wid * 1024);
  // stage C step 0
#pragma unroll
  for (int r = 0; r < 2; ++r) {
    int brow = r * 64 + (tid >> 3);
    int sc = (tid & 7) ^ (brow & 7);
    gl_lds16(cw + (size_t)(col0 + brow) * 256 + 0 + sc * 8,
             (char*)CS + r * 8192 + wid * 1024);
  }
  __syncthreads();

  // ---- recon xs in place: 2 chunk halves x 256 states ----
  {
    const int hf = tid >> 8;        // 0/1
    const int s = tid & 255;
    const float a = af[s];
    float x = initb[(size_t)(bx * 2 + hf) * 256 + s];
    const int r0 = hf * 64;
    const int slot = s >> 3;
    const int off = (s & 7);
#pragma unroll 8
    for (int t = 0; t < 64; ++t) {
      int r = r0 + t;
      int bi = r * 256 + ((slot ^ (r & 7)) * 8) + off;
      x = fmaf(a, x, bf2f(XS[bi]));
      XS[bi] = f2bf(x);
    }
  }

  // ---- init acc from ud (global, overlaps recon of other waves) ----
  f32x4 acc[4][2];
#pragma unroll
  for (int mi = 0; mi < 4; ++mi) {
    int rlb = wr * 64 + mi * 16 + (lane >> 4) * 4;
#pragma unroll
    for (int ni = 0; ni < 2; ++ni) {
      int col = col0 + wc * 32 + ni * 16 + (lane & 15);
#pragma unroll
      for (int q = 0; q < 4; ++q)
        acc[mi][ni][q] = bf2f(ud[(size_t)(bx * 128 + rlb + q) * 256 + col]);
    }
  }
  __syncthreads();

  // ---- K loop over c (K=256, 4 steps) ----
#pragma unroll
  for (int kt = 0; kt < 4; ++kt) {
#pragma unroll
    for (int kk = 0; kk < 2; ++kk) {
      const int ksl = kk * 4 + (lane >> 4);       // local slot in CS
      const int ksg = kt * 8 + ksl;               // global slot in XS
      bf16x8 afr[4], bfr[2];
#pragma unroll
      for (int mi = 0; mi < 4; ++mi) {
        int ar = wr * 64 + mi * 16 + (lane & 15);
        afr[mi] = *reinterpret_cast<const bf16x8*>(&XS[ar * 256 + ((ksg ^ (ar & 7)) * 8)]);
      }
#pragma unroll
      for (int ni = 0; ni < 2; ++ni) {
        int nr = wc * 32 + ni * 16 + (lane & 15);
        bfr[ni] = *reinterpret_cast<const bf16x8*>(&CS[nr * 64 + ((ksl ^ (nr & 7)) * 8)]);
      }
#pragma unroll
      for (int mi = 0; mi < 4; ++mi)
#pragma unroll
        for (int ni = 0; ni < 2; ++ni)
          acc[mi][ni] = __builtin_amdgcn_mfma_f32_16x16x32_bf16(
              afr[mi], bfr[ni], acc[mi][ni], 0, 0, 0);
    }
    if (kt < 3) {
      __syncthreads();  // readers done with CS
#pragma unroll
      for (int r = 0; r < 2; ++r) {
        int brow = r * 64 + (tid >> 3);
        int sc = (tid & 7) ^ (brow & 7);
        gl_lds16(cw + (size_t)(col0 + brow) * 256 + (kt + 1) * 64 + sc * 8,
                 (char*)CS + r * 8192 + wid * 1024);
      }
      __syncthreads();  // staged (vmcnt drained)
    }
  }

  // ---- epilogue: y fp32 ----
#pragma unroll
  for (int mi = 0; mi < 4; ++mi) {
    int rlb = wr * 64 + mi * 16 + (lane >> 4) * 4;
#pragma unroll
    for (int ni = 0; ni < 2; ++ni) {
      int col = col0 + wc * 32 + ni * 16 + (lane & 15);
#pragma unroll
      for (int q = 0; q < 4; ++q)
        y[(size_t)(bx * 128 + rlb + q) * 256 + col] = acc[mi][ni][q];
    }
  }
}

extern "C" void kernel_launch(void* const* d_in, const int* in_sizes, int n_in,
                              void* d_out, int out_size, void* d_ws, size_t ws_size,
                              hipStream_t stream) {
  const float* u = (const float*)d_in[0];
  const float* a_raw = (const float*)d_in[1];
  const float* b = (const float*)d_in[2];
  const float* c = (const float*)d_in[3];
  const float* d = (const float*)d_in[4];
  float* y = (float*)d_out;
  char* ws = (char*)d_ws;

  const size_t MB = 1u << 20;
  float* af = (float*)(ws);                       // 1 KB
  u16* wq = (u16*)(ws + 65536);                   // 256 KB  [b;d] stacked
  u16* cw = (u16*)(ws + 65536 + 262144);          // 128 KB
  u16* bu = (u16*)(ws + 1 * MB);                  // 32 MB (swizzled)
  u16* ud = (u16*)(ws + 33 * MB);                 // 32 MB
  float* carry = (float*)(ws + 65 * MB);          // 1 MB
  float* initb = (float*)(ws + 66 * MB);          // 1 MB

  prep_k<<<256, 256, 0, stream>>>(a_raw, b, c, d, af, wq, cw);
  gemm1_k<<<1024, 1024, 0, stream>>>(u, wq, af, bu, ud, carry);
  scan2_k<<<16, 256, 0, stream>>>(carry, af, initb);
  gemm2_k<<<dim3(512, 2), 512, 0, stream>>>(bu, cw, ud, af, initb, y);
}